// Round 1
// baseline (647.364 us; speedup 1.0000x reference)
//
#include <hip/hip_runtime.h>
#include <hip/hip_bf16.h>
#include <math.h>

#define B_  4
#define S_  2048
#define D_  1024
#define H_  16
#define HD_ 64
#define SD_  (S_*D_)        // 2097152
#define SHD_ (S_*HD_)       // 131072

typedef __attribute__((ext_vector_type(8))) short          bf16x8;   // MFMA A/B frag (4 VGPRs)
typedef __attribute__((ext_vector_type(4))) float          f32x4;    // MFMA C/D frag
typedef __attribute__((ext_vector_type(8))) unsigned short us8;
typedef __attribute__((ext_vector_type(4))) unsigned short us4;

__device__ __forceinline__ unsigned short f2bf(float x) {  // RNE float->bf16
  unsigned int u = __float_as_uint(x);
  u += 0x7fffu + ((u >> 16) & 1u);
  return (unsigned short)(u >> 16);
}
__device__ __forceinline__ float bf2f(unsigned short u) {
  return __uint_as_float(((unsigned int)u) << 16);
}

// async global->LDS, 16B per lane: wave-uniform LDS base + lane*16 (m104).
__device__ __forceinline__ void gload16(const unsigned short* g, unsigned short* l) {
  __builtin_amdgcn_global_load_lds(
      (const __attribute__((address_space(1))) unsigned int*)g,
      (__attribute__((address_space(3))) unsigned int*)l,
      16, 0, 0);
}

// ---------------------------------------------------------------------------
// fp32 -> bf16 converts
// ---------------------------------------------------------------------------
__global__ __launch_bounds__(256) void cvt_a(const float* __restrict__ s,
                                             unsigned short* __restrict__ d)
{
  int i = blockIdx.x * 256 + threadIdx.x;          // float4 index
  float4 v = ((const float4*)s)[i];
  us4 o = { f2bf(v.x), f2bf(v.y), f2bf(v.z), f2bf(v.w) };
  *(us4*)(d + (size_t)i * 4) = o;
}

__global__ __launch_bounds__(256) void cvt_w(const float* __restrict__ w0,
                                             const float* __restrict__ w1,
                                             const float* __restrict__ w2,
                                             const float* __restrict__ w3,
                                             unsigned short* __restrict__ dst)
{
  const float* s = (blockIdx.y == 0) ? w0 : (blockIdx.y == 1) ? w1
                 : (blockIdx.y == 2) ? w2 : w3;
  unsigned short* d = dst + (size_t)blockIdx.y * 1024 * 1024;
  int i = blockIdx.x * 256 + threadIdx.x;
  float4 v = ((const float4*)s)[i];
  us4 o = { f2bf(v.x), f2bf(v.y), f2bf(v.z), f2bf(v.w) };
  *(us4*)(d + (size_t)i * 4) = o;
}

// ---------------------------------------------------------------------------
// bf16 MFMA GEMM (m97 structure): C[8192,1024] = A @ W^T + bias, bf16 out
// (flat row-major — correct for the reference's flat head-view by construction).
// 128x128 tile, BK=32, 256 thr = 4 waves (2x2), 4x4 16x16 tiles per wave.
// ---------------------------------------------------------------------------
__global__ __launch_bounds__(256) void gemm_mfma(
    const unsigned short* __restrict__ A,    // [8192,1024] bf16
    const unsigned short* __restrict__ Wb,   // [1024,1024] bf16, row n = out col
    const float* __restrict__ bias,
    unsigned short* __restrict__ Cb)
{
  __shared__ unsigned short As[128 * 32];   // [row][k] 8 KB
  __shared__ unsigned short Bs[128 * 32];   // [ncol][k] 8 KB

  const int tid  = threadIdx.x;
  const int lane = tid & 63;
  const int w    = tid >> 6;
  const int wm   = w >> 1, wn = w & 1;
  const int l16  = lane & 15, quad = lane >> 4;
  const int n0 = blockIdx.x * 128;
  const int m0 = blockIdx.y * 128;

  f32x4 acc[4][4];
#pragma unroll
  for (int mt = 0; mt < 4; ++mt)
#pragma unroll
    for (int nt = 0; nt < 4; ++nt) acc[mt][nt] = (f32x4){0.f, 0.f, 0.f, 0.f};

  const int srow = lane >> 2;          // 0..15 row within 16-row slab
  const int sseg = (lane & 3) * 8;     // ushort offset within 32-elem row

  for (int kt = 0; kt < 32; ++kt) {
    const int kofs = kt * 32;
#pragma unroll
    for (int t = 0; t < 2; ++t) {
      const int r = w * 32 + t * 16 + srow;          // 0..127
      gload16(A  + (size_t)(m0 + r) * 1024 + kofs + sseg, &As[r * 32 + sseg]);
      gload16(Wb + (size_t)(n0 + r) * 1024 + kofs + sseg, &Bs[r * 32 + sseg]);
    }
    __syncthreads();   // drains vmcnt (global_load_lds) + barrier

    bf16x8 af[4], bfr[4];
#pragma unroll
    for (int mt = 0; mt < 4; ++mt)
      af[mt] = *(const bf16x8*)&As[(wm * 64 + mt * 16 + l16) * 32 + quad * 8];
#pragma unroll
    for (int nt = 0; nt < 4; ++nt)
      bfr[nt] = *(const bf16x8*)&Bs[(wn * 64 + nt * 16 + l16) * 32 + quad * 8];
#pragma unroll
    for (int mt = 0; mt < 4; ++mt)
#pragma unroll
      for (int nt = 0; nt < 4; ++nt)
        acc[mt][nt] = __builtin_amdgcn_mfma_f32_16x16x32_bf16(
            af[mt], bfr[nt], acc[mt][nt], 0, 0, 0);
    __syncthreads();   // frag reads done before next stage overwrites
  }

  // C-layout: col=l16, row=quad*4+reg  (m89-verified)
#pragma unroll
  for (int nt = 0; nt < 4; ++nt) {
    const int ncol = n0 + wn * 64 + nt * 16 + l16;
    const float bv = bias[ncol];
#pragma unroll
    for (int mt = 0; mt < 4; ++mt) {
      const int row = m0 + wm * 64 + mt * 16 + quad * 4;
#pragma unroll
      for (int reg = 0; reg < 4; ++reg)
        Cb[(size_t)(row + reg) * 1024 + ncol] = f2bf(acc[mt][nt][reg] + bv);
    }
  }
}

// ---------------------------------------------------------------------------
// V transpose: Vt[bh][d][s] = Vflat[bh*131072 + s*64 + d]  (pure flat indices,
// so the reference's scrambled head-view is handled automatically).
// ---------------------------------------------------------------------------
__global__ __launch_bounds__(256) void vtrans(
    const unsigned short* __restrict__ V, unsigned short* __restrict__ Vt)
{
  __shared__ unsigned short t[64][72];   // t[s][d], padded rows
  const int tid = threadIdx.x;
  const int st  = blockIdx.x;            // s-tile 0..31
  const int bh  = blockIdx.y;            // 0..63
  const unsigned short* src = V + (size_t)bh * SHD_ + (size_t)st * 4096;

#pragma unroll
  for (int u = tid; u < 512; u += 256) {           // 512 us8 chunks = 8 KB
    us8 vv = ((const us8*)src)[u];
    int s  = u >> 3;
    int dg = (u & 7) * 8;
    *(us8*)&t[s][dg] = vv;
  }
  __syncthreads();

  unsigned short* dst = Vt + (size_t)bh * SHD_ + st * 64;
#pragma unroll
  for (int u = tid; u < 1024; u += 256) {          // 64 d-rows x 16 us4 chunks
    int d  = u >> 4;
    int s4 = (u & 15) * 4;
    us4 o = { t[s4][d], t[s4 + 1][d], t[s4 + 2][d], t[s4 + 3][d] };
    *(us4*)(dst + (size_t)d * 2048 + s4) = o;
  }
}

// ---------------------------------------------------------------------------
// Barrier-free MFMA flash attention, DIAGONAL PAIRING + DUAL-CHAIN ILP.
// WG p (0..15) processes Q-tiles {p, 31-p}. Within each tile, KV tiles are
// split into TWO independent online-softmax chains (A = even jt, B = odd jt),
// each with its own (m, l, O) state, merged at the epilogue. The two chains'
// MFMA / shuffle-tree / exp / LDS round-trips interleave in the scheduler,
// attacking the latency-bound serial chain (MfmaUtil 5.6%, VALUBusy 25%).
// Per-WG dual-iteration count is uniform: ceil((p+1)/2)+ceil((32-p)/2) = 17.
// NOTE: running max inits to -1e30 (NOT -inf): chain B starts at jt=1 which
// can be a fully-padded tile; -inf - -inf = NaN.
// ---------------------------------------------------------------------------
__global__ __launch_bounds__(256, 4) void attn_mfma(
    unsigned short* __restrict__ Qb, const unsigned short* __restrict__ Kb,
    const unsigned short* __restrict__ Vt, const int* __restrict__ pad)
{
  __shared__ unsigned short Ps[4][2][16][72];  // per-wave, per-chain P strip (18 KB)

  const int tid  = threadIdx.x;
  const int lane = tid & 63;
  const int w    = tid >> 6;
  const int p    = blockIdx.x;     // pair index 0..15
  const int bh   = blockIdx.y;     // 0..63
  const int b    = bh >> 4;
  const size_t base = (size_t)bh * SHD_;

  const int l16  = lane & 15;
  const int quad = lane >> 4;

  for (int half = 0; half < 2; ++half) {
    const int it = half ? (31 - p) : p;

    bf16x8 qfrag[2];
    {
      const unsigned short* qrow = Qb + base + (size_t)(it * 64 + w * 16 + l16) * 64;
      qfrag[0] = *(const bf16x8*)(qrow + quad * 8);
      qfrag[1] = *(const bf16x8*)(qrow + 32 + quad * 8);
    }

    f32x4 oacc[2][4];
    float mrow[2][4], lrow[2][4];
#pragma unroll
    for (int c = 0; c < 2; ++c)
#pragma unroll
      for (int r = 0; r < 4; ++r) {
        oacc[c][r] = (f32x4){0.f, 0.f, 0.f, 0.f};
        mrow[c][r] = -1e30f;   // finite: see NaN note above
        lrow[c][r] = 0.f;
      }

    for (int jt0 = 0; jt0 <= it; jt0 += 2) {
      const bool doB = (jt0 + 1 <= it);

      // ---- QK^T, both chains (K B-frags direct from global, L2-hot) ----
      f32x4 sacc[2][4];
#pragma unroll
      for (int c = 0; c < 2; ++c) {
        if (c == 0 || doB) {
          const int jt = jt0 + c;
#pragma unroll
          for (int ct = 0; ct < 4; ++ct) {
            const unsigned short* krow = Kb + base + (size_t)(jt * 64 + ct * 16 + l16) * 64;
            bf16x8 k0 = *(const bf16x8*)(krow + quad * 8);
            bf16x8 k1 = *(const bf16x8*)(krow + 32 + quad * 8);
            f32x4 s = (f32x4){0.f, 0.f, 0.f, 0.f};
            s = __builtin_amdgcn_mfma_f32_16x16x32_bf16(qfrag[0], k0, s, 0, 0, 0);
            s = __builtin_amdgcn_mfma_f32_16x16x32_bf16(qfrag[1], k1, s, 0, 0, 0);
            sacc[c][ct] = s;
          }
        }
      }

      // ---- masked online softmax, both chains (independent shuffle trees
      //      interleave across chains) ----
      float alpha[2][4];
#pragma unroll
      for (int c = 0; c < 2; ++c) {
        if (c == 0 || doB) {
          const int jt = jt0 + c;
          int padv[4];
#pragma unroll
          for (int ct = 0; ct < 4; ++ct)
            padv[ct] = pad[b * S_ + jt * 64 + ct * 16 + l16];

          const int grow0 = it * 64 + w * 16 + quad * 4;
#pragma unroll
          for (int reg = 0; reg < 4; ++reg) {
            const int gi = grow0 + reg;
            float lg[4];
            float mx = -INFINITY;
#pragma unroll
            for (int ct = 0; ct < 4; ++ct) {
              int gj = jt * 64 + ct * 16 + l16;
              bool ok = (gj <= gi) && (padv[ct] != 0);
              lg[ct] = ok ? sacc[c][ct][reg] * 0.125f : -INFINITY;
              mx = fmaxf(mx, lg[ct]);
            }
#pragma unroll
            for (int off = 1; off < 16; off <<= 1) mx = fmaxf(mx, __shfl_xor(mx, off, 64));
            float mnew = fmaxf(mrow[c][reg], mx);      // finite: mrow >= -1e30
            float a    = __expf(mrow[c][reg] - mnew);
            float sm   = 0.f;
#pragma unroll
            for (int ct = 0; ct < 4; ++ct) {
              float pe = __expf(lg[ct] - mnew);
              sm += pe;
              Ps[w][c][quad * 4 + reg][ct * 16 + l16] = f2bf(pe);
            }
#pragma unroll
            for (int off = 1; off < 16; off <<= 1) sm += __shfl_xor(sm, off, 64);
            lrow[c][reg]  = lrow[c][reg] * a + sm;
            mrow[c][reg]  = mnew;
            alpha[c][reg] = a;
          }
        }
      }

      // ---- rescale old O by alpha ----
#pragma unroll
      for (int c = 0; c < 2; ++c) {
        if (c == 0 || doB) {
#pragma unroll
          for (int dt = 0; dt < 4; ++dt)
#pragma unroll
            for (int reg = 0; reg < 4; ++reg) oacc[c][dt][reg] *= alpha[c][reg];
        }
      }

      // ---- PV chain A (V^T frags loaded inline; B's loads fly under A's MFMAs) ----
      {
        bf16x8 pf0 = *(const bf16x8*)&Ps[w][0][l16][quad * 8];
        bf16x8 pf1 = *(const bf16x8*)&Ps[w][0][l16][32 + quad * 8];
#pragma unroll
        for (int dt = 0; dt < 4; ++dt) {
          const unsigned short* vrow = Vt + base + (size_t)(dt * 16 + l16) * 2048 + jt0 * 64;
          bf16x8 v0 = *(const bf16x8*)(vrow + quad * 8);
          bf16x8 v1 = *(const bf16x8*)(vrow + 32 + quad * 8);
          oacc[0][dt] = __builtin_amdgcn_mfma_f32_16x16x32_bf16(pf0, v0, oacc[0][dt], 0, 0, 0);
          oacc[0][dt] = __builtin_amdgcn_mfma_f32_16x16x32_bf16(pf1, v1, oacc[0][dt], 0, 0, 0);
        }
      }
      // ---- PV chain B ----
      if (doB) {
        bf16x8 pf0 = *(const bf16x8*)&Ps[w][1][l16][quad * 8];
        bf16x8 pf1 = *(const bf16x8*)&Ps[w][1][l16][32 + quad * 8];
#pragma unroll
        for (int dt = 0; dt < 4; ++dt) {
          const unsigned short* vrow = Vt + base + (size_t)(dt * 16 + l16) * 2048 + (jt0 + 1) * 64;
          bf16x8 v0 = *(const bf16x8*)(vrow + quad * 8);
          bf16x8 v1 = *(const bf16x8*)(vrow + 32 + quad * 8);
          oacc[1][dt] = __builtin_amdgcn_mfma_f32_16x16x32_bf16(pf0, v0, oacc[1][dt], 0, 0, 0);
          oacc[1][dt] = __builtin_amdgcn_mfma_f32_16x16x32_bf16(pf1, v1, oacc[1][dt], 0, 0, 0);
        }
      }
    }

    // ---- epilogue: merge the two chains, normalize, write bf16 in place ----
    // m = max(mA,mB); wC = exp(mC-m); O = (OA*wA + OB*wB) / (lA*wA + lB*wB)
#pragma unroll
    for (int reg = 0; reg < 4; ++reg) {
      const float mA = mrow[0][reg], mB = mrow[1][reg];
      const float m  = fmaxf(mA, mB);
      const float wA = __expf(mA - m);
      const float wB = __expf(mB - m);     // 0 when chain B never ran
      const float l  = lrow[0][reg] * wA + lrow[1][reg] * wB;
      const float rl = 1.0f / l;
      unsigned short* orow = Qb + base + (size_t)(it * 64 + w * 16 + quad * 4 + reg) * 64;
#pragma unroll
      for (int dt = 0; dt < 4; ++dt)
        orow[dt * 16 + l16] = f2bf((oacc[0][dt][reg] * wA + oacc[1][dt][reg] * wB) * rl);
    }
  }
}

// ---------------------------------------------------------------------------
// Residual + LayerNorm; O is bf16.
// ---------------------------------------------------------------------------
__global__ __launch_bounds__(256) void ln_kernel(
    const float* __restrict__ x, const unsigned short* __restrict__ O,
    const float* __restrict__ gamma, const float* __restrict__ beta,
    float* __restrict__ out)
{
  __shared__ float red[8];
  const int row = blockIdx.x;
  const int tid = threadIdx.x;
  float4 xv = ((const float4*)x)[(size_t)row * 256 + tid];
  us4 ov4 = *(const us4*)(O + (size_t)row * 1024 + tid * 4);
  float4 y = make_float4(xv.x + bf2f(ov4[0]), xv.y + bf2f(ov4[1]),
                         xv.z + bf2f(ov4[2]), xv.w + bf2f(ov4[3]));
  float s1 = y.x + y.y + y.z + y.w;
  float s2 = y.x*y.x + y.y*y.y + y.z*y.z + y.w*y.w;
#pragma unroll
  for (int off = 32; off >= 1; off >>= 1) {
    s1 += __shfl_xor(s1, off, 64);
    s2 += __shfl_xor(s2, off, 64);
  }
  if ((tid & 63) == 0) { red[tid >> 6] = s1; red[4 + (tid >> 6)] = s2; }
  __syncthreads();
  s1 = red[0] + red[1] + red[2] + red[3];
  s2 = red[4] + red[5] + red[6] + red[7];
  const float mean = s1 * (1.0f / 1024.0f);
  const float var  = fmaxf(s2 * (1.0f / 1024.0f) - mean * mean, 0.f);
  const float rstd = 1.0f / (sqrtf(var) + 1e-8f);
  float4 gv = ((const float4*)gamma)[tid];
  float4 bv = ((const float4*)beta)[tid];
  float4 r;
  r.x = gv.x * (y.x - mean) * rstd + bv.x;
  r.y = gv.y * (y.y - mean) * rstd + bv.y;
  r.z = gv.z * (y.z - mean) * rstd + bv.z;
  r.w = gv.w * (y.w - mean) * rstd + bv.w;
  ((float4*)out)[(size_t)row * 256 + tid] = r;
}

// ---------------------------------------------------------------------------
extern "C" void kernel_launch(void* const* d_in, const int* in_sizes, int n_in,
                              void* d_out, int out_size, void* d_ws, size_t ws_size,
                              hipStream_t stream)
{
  const float* q  = (const float*)d_in[0];
  const float* k  = (const float*)d_in[1];
  const float* v  = (const float*)d_in[2];
  // d_in[3] = causal tril mask — applied analytically (j<=i)
  const int*   pad = (const int*)d_in[4];
  const float* Wq = (const float*)d_in[5];
  const float* bq = (const float*)d_in[6];
  const float* Wk = (const float*)d_in[7];
  const float* bk = (const float*)d_in[8];
  const float* Wv = (const float*)d_in[9];
  const float* bv = (const float*)d_in[10];
  const float* Wo = (const float*)d_in[11];
  const float* bo = (const float*)d_in[12];
  const float* gamma = (const float*)d_in[13];
  const float* beta  = (const float*)d_in[14];
  float* out = (float*)d_out;

  char* ws = (char*)d_ws;
  const size_t MB = 1024 * 1024;
  unsigned short* Ac   = (unsigned short*)(ws);             // 16 MB bf16 staging
  unsigned short* Qb   = (unsigned short*)(ws + 16 * MB);   // 16 MB
  unsigned short* Kb   = (unsigned short*)(ws + 32 * MB);   // 16 MB
  unsigned short* Vb   = (unsigned short*)(ws + 48 * MB);   // 16 MB (flat V)
  unsigned short* Vtb  = (unsigned short*)(ws + 64 * MB);   // 16 MB (V^T per bh)
  unsigned short* Wall = (unsigned short*)(ws + 80 * MB);   // 8 MB (4 weights bf16)
  unsigned short* Obuf = Ac;                                // alias: Ac dead after V-GEMM

  dim3 gg(8, 64), bb(256);
  cvt_w<<<dim3(1024, 4), 256, 0, stream>>>(Wq, Wk, Wv, Wo, Wall);

  cvt_a<<<8192, 256, 0, stream>>>(q, Ac);
  gemm_mfma<<<gg, bb, 0, stream>>>(Ac, Wall + 0 * MB, bq, Qb);
  cvt_a<<<8192, 256, 0, stream>>>(k, Ac);
  gemm_mfma<<<gg, bb, 0, stream>>>(Ac, Wall + 1 * MB, bk, Kb);
  cvt_a<<<8192, 256, 0, stream>>>(v, Ac);
  gemm_mfma<<<gg, bb, 0, stream>>>(Ac, Wall + 2 * MB, bv, Vb);
  vtrans<<<dim3(32, 64), 256, 0, stream>>>(Vb, Vtb);

  attn_mfma<<<dim3(16, 64), 256, 0, stream>>>(Qb, Kb, Vtb, pad);  // Qb <- attn out

  gemm_mfma<<<gg, bb, 0, stream>>>(Qb, Wall + 3 * MB, bo, Obuf);
  ln_kernel<<<dim3(B_ * S_), 256, 0, stream>>>(q, Obuf, gamma, beta, out);
}

// Round 2
// 432.652 us; speedup vs baseline: 1.4963x; 1.4963x over previous
//
#include <hip/hip_runtime.h>
#include <hip/hip_bf16.h>
#include <math.h>

#define B_  4
#define S_  2048
#define D_  1024
#define H_  16
#define HD_ 64
#define SD_  (S_*D_)        // 2097152
#define SHD_ (S_*HD_)       // 131072

typedef __attribute__((ext_vector_type(8))) short          bf16x8;   // MFMA A/B frag (4 VGPRs)
typedef __attribute__((ext_vector_type(4))) float          f32x4;    // MFMA C/D frag
typedef __attribute__((ext_vector_type(8))) unsigned short us8;
typedef __attribute__((ext_vector_type(4))) unsigned short us4;

__device__ __forceinline__ unsigned short f2bf(float x) {  // RNE float->bf16
  unsigned int u = __float_as_uint(x);
  u += 0x7fffu + ((u >> 16) & 1u);
  return (unsigned short)(u >> 16);
}
__device__ __forceinline__ float bf2f(unsigned short u) {
  return __uint_as_float(((unsigned int)u) << 16);
}

// async global->LDS, 16B per lane: wave-uniform LDS base + lane*16 (m104).
__device__ __forceinline__ void gload16(const unsigned short* g, unsigned short* l) {
  __builtin_amdgcn_global_load_lds(
      (const __attribute__((address_space(1))) unsigned int*)g,
      (__attribute__((address_space(3))) unsigned int*)l,
      16, 0, 0);
}

// ---------------------------------------------------------------------------
// Stage a 64-row x 128-byte tile global->LDS with XOR-swizzled SOURCE, so
// that swizzled ds_reads (byte ^= (row&7)<<4) observe linear global data.
// Rule #21: gload_lds writes linearly (base+lane*16); the swizzle must be
// applied on the per-lane GLOBAL address (m173 pattern) + on the read side.
// 512 chunks of 16B, 256 threads -> 2 rounds.
// ---------------------------------------------------------------------------
__device__ __forceinline__ void stage_swz(const unsigned short* __restrict__ g,
                                          int rstride /*elems*/,
                                          unsigned short* lds, int tid)
{
#pragma unroll
  for (int rr = 0; rr < 2; ++rr) {
    const int cidx = tid + rr * 256;               // 16B chunk index 0..511
    const int row  = cidx >> 3;                    // 0..63
    const int sb   = ((cidx & 7) * 16) ^ ((row & 7) << 4);  // swizzled src byte
    gload16(g + (size_t)row * rstride + (sb >> 1), lds + cidx * 8);
  }
}

// read one MFMA B-frag pair (cols [0,64) and [64,128) bytes of a tile row)
// from a swizzle-stored LDS tile.
__device__ __forceinline__ void read_frag_pair(const unsigned short* lds, int row,
                                               int quad, bf16x8& f0, bf16x8& f1)
{
  const int sw = (row & 7) << 4;
  const unsigned short* p = lds + row * 64;
  f0 = *(const bf16x8*)(p + (((quad * 16) ^ sw) >> 1));
  f1 = *(const bf16x8*)(p + (((64 + quad * 16) ^ sw) >> 1));
}

// ---------------------------------------------------------------------------
// fp32 -> bf16 converts
// ---------------------------------------------------------------------------
__global__ __launch_bounds__(256) void cvt_a(const float* __restrict__ s,
                                             unsigned short* __restrict__ d)
{
  int i = blockIdx.x * 256 + threadIdx.x;          // float4 index
  float4 v = ((const float4*)s)[i];
  us4 o = { f2bf(v.x), f2bf(v.y), f2bf(v.z), f2bf(v.w) };
  *(us4*)(d + (size_t)i * 4) = o;
}

__global__ __launch_bounds__(256) void cvt_w(const float* __restrict__ w0,
                                             const float* __restrict__ w1,
                                             const float* __restrict__ w2,
                                             const float* __restrict__ w3,
                                             unsigned short* __restrict__ dst)
{
  const float* s = (blockIdx.y == 0) ? w0 : (blockIdx.y == 1) ? w1
                 : (blockIdx.y == 2) ? w2 : w3;
  unsigned short* d = dst + (size_t)blockIdx.y * 1024 * 1024;
  int i = blockIdx.x * 256 + threadIdx.x;
  float4 v = ((const float4*)s)[i];
  us4 o = { f2bf(v.x), f2bf(v.y), f2bf(v.z), f2bf(v.w) };
  *(us4*)(d + (size_t)i * 4) = o;
}

// ---------------------------------------------------------------------------
// bf16 MFMA GEMM (m97 structure): C[8192,1024] = A @ W^T + bias, bf16 out
// 128x128 tile, BK=32, 256 thr = 4 waves (2x2), 4x4 16x16 tiles per wave.
// ---------------------------------------------------------------------------
__global__ __launch_bounds__(256) void gemm_mfma(
    const unsigned short* __restrict__ A,    // [8192,1024] bf16
    const unsigned short* __restrict__ Wb,   // [1024,1024] bf16, row n = out col
    const float* __restrict__ bias,
    unsigned short* __restrict__ Cb)
{
  __shared__ unsigned short As[128 * 32];   // [row][k] 8 KB
  __shared__ unsigned short Bs[128 * 32];   // [ncol][k] 8 KB

  const int tid  = threadIdx.x;
  const int lane = tid & 63;
  const int w    = tid >> 6;
  const int wm   = w >> 1, wn = w & 1;
  const int l16  = lane & 15, quad = lane >> 4;
  const int n0 = blockIdx.x * 128;
  const int m0 = blockIdx.y * 128;

  f32x4 acc[4][4];
#pragma unroll
  for (int mt = 0; mt < 4; ++mt)
#pragma unroll
    for (int nt = 0; nt < 4; ++nt) acc[mt][nt] = (f32x4){0.f, 0.f, 0.f, 0.f};

  const int srow = lane >> 2;          // 0..15 row within 16-row slab
  const int sseg = (lane & 3) * 8;     // ushort offset within 32-elem row

  for (int kt = 0; kt < 32; ++kt) {
    const int kofs = kt * 32;
#pragma unroll
    for (int t = 0; t < 2; ++t) {
      const int r = w * 32 + t * 16 + srow;          // 0..127
      gload16(A  + (size_t)(m0 + r) * 1024 + kofs + sseg, &As[r * 32 + sseg]);
      gload16(Wb + (size_t)(n0 + r) * 1024 + kofs + sseg, &Bs[r * 32 + sseg]);
    }
    __syncthreads();   // drains vmcnt (global_load_lds) + barrier

    bf16x8 af[4], bfr[4];
#pragma unroll
    for (int mt = 0; mt < 4; ++mt)
      af[mt] = *(const bf16x8*)&As[(wm * 64 + mt * 16 + l16) * 32 + quad * 8];
#pragma unroll
    for (int nt = 0; nt < 4; ++nt)
      bfr[nt] = *(const bf16x8*)&Bs[(wn * 64 + nt * 16 + l16) * 32 + quad * 8];
#pragma unroll
    for (int mt = 0; mt < 4; ++mt)
#pragma unroll
      for (int nt = 0; nt < 4; ++nt)
        acc[mt][nt] = __builtin_amdgcn_mfma_f32_16x16x32_bf16(
            af[mt], bfr[nt], acc[mt][nt], 0, 0, 0);
    __syncthreads();   // frag reads done before next stage overwrites
  }

  // C-layout: col=l16, row=quad*4+reg  (m89-verified)
#pragma unroll
  for (int nt = 0; nt < 4; ++nt) {
    const int ncol = n0 + wn * 64 + nt * 16 + l16;
    const float bv = bias[ncol];
#pragma unroll
    for (int mt = 0; mt < 4; ++mt) {
      const int row = m0 + wm * 64 + mt * 16 + quad * 4;
#pragma unroll
      for (int reg = 0; reg < 4; ++reg)
        Cb[(size_t)(row + reg) * 1024 + ncol] = f2bf(acc[mt][nt][reg] + bv);
    }
  }
}

// ---------------------------------------------------------------------------
// V transpose: Vt[bh][d][s] = Vflat[bh*131072 + s*64 + d]
// ---------------------------------------------------------------------------
__global__ __launch_bounds__(256) void vtrans(
    const unsigned short* __restrict__ V, unsigned short* __restrict__ Vt)
{
  __shared__ unsigned short t[64][72];   // t[s][d], padded rows
  const int tid = threadIdx.x;
  const int st  = blockIdx.x;            // s-tile 0..31
  const int bh  = blockIdx.y;            // 0..63
  const unsigned short* src = V + (size_t)bh * SHD_ + (size_t)st * 4096;

#pragma unroll
  for (int u = tid; u < 512; u += 256) {           // 512 us8 chunks = 8 KB
    us8 vv = ((const us8*)src)[u];
    int s  = u >> 3;
    int dg = (u & 7) * 8;
    *(us8*)&t[s][dg] = vv;
  }
  __syncthreads();

  unsigned short* dst = Vt + (size_t)bh * SHD_ + st * 64;
#pragma unroll
  for (int u = tid; u < 1024; u += 256) {          // 64 d-rows x 16 us4 chunks
    int d  = u >> 4;
    int s4 = (u & 15) * 4;
    us4 o = { t[s4][d], t[s4 + 1][d], t[s4 + 2][d], t[s4 + 3][d] };
    *(us4*)(dst + (size_t)d * 2048 + s4) = o;
  }
}

// ---------------------------------------------------------------------------
// MFMA flash attention, DIAGONAL PAIRING + LDS-STAGED K/V (2-phase pipeline).
// WG p (0..15) processes Q-tiles {p, 31-p} -> 33 j-iterations per WG.
// Per iteration:
//   barrier-1 (drains vmcnt: staged tile + pad prefetch landed)
//   ds_read K frags (swizzled) -> QK^T MFMAs
//   barrier-2 + issue stage(jt+1): K -> Ks (single buf), V -> Vs[cur^1]
//     (staging latency hides under softmax+PV; V is double-buffered so
//      PV reads Vs[cur] safely)
//   online softmax (pad prefetched last iter; causal analytic)
//   PV MFMAs reading V frags from Vs[cur]
// XOR swizzle (byte ^= (row&7)<<4) on both stage-source and ds_read kills the
// 16-way bank conflict of row-major [64][64]bf16 tiles (G4 / rule #21).
// Single softmax chain: round-1's dual chain spilled (WRITE_SIZE 566MB).
// ---------------------------------------------------------------------------
__global__ __launch_bounds__(256, 4) void attn_mfma(
    unsigned short* __restrict__ Qb, const unsigned short* __restrict__ Kb,
    const unsigned short* __restrict__ Vt, const int* __restrict__ pad)
{
  __shared__ unsigned short Ks[64 * 64];        // 8 KB, single-buffered
  __shared__ unsigned short Vs[2][64 * 64];     // 16 KB, double-buffered
  __shared__ unsigned short Ps[4][16][72];      // per-wave P strip, 9 KB

  const int tid  = threadIdx.x;
  const int lane = tid & 63;
  const int w    = tid >> 6;
  const int p    = blockIdx.x;     // pair index 0..15
  const int bh   = blockIdx.y;     // 0..63
  const int b    = bh >> 4;
  const size_t base = (size_t)bh * SHD_;

  const int l16  = lane & 15;
  const int quad = lane >> 4;

  for (int half = 0; half < 2; ++half) {
    const int it = half ? (31 - p) : p;

    bf16x8 qfrag[2];
    {
      const unsigned short* qrow = Qb + base + (size_t)(it * 64 + w * 16 + l16) * 64;
      qfrag[0] = *(const bf16x8*)(qrow + quad * 8);
      qfrag[1] = *(const bf16x8*)(qrow + 32 + quad * 8);
    }

    f32x4 oacc[4];
#pragma unroll
    for (int dt = 0; dt < 4; ++dt) oacc[dt] = (f32x4){0.f, 0.f, 0.f, 0.f};
    float mrow[4], lrow[4];
#pragma unroll
    for (int r = 0; r < 4; ++r) { mrow[r] = -INFINITY; lrow[r] = 0.f; }

    // ---- half prologue: protect LDS from previous half, stage tile 0 ----
    __syncthreads();
    stage_swz(Kb + base, 64, Ks, tid);
    stage_swz(Vt + base, 2048, Vs[0], tid);
    int padv[4];
#pragma unroll
    for (int ct = 0; ct < 4; ++ct) padv[ct] = pad[b * S_ + ct * 16 + l16];
    int cur = 0;

    for (int jt = 0; jt <= it; ++jt) {
      __syncthreads();   // barrier-1: staged K/V(jt) + pad(jt) landed (vmcnt drain)

      // ---- QK^T from LDS K tile ----
      f32x4 sacc[4];
#pragma unroll
      for (int ct = 0; ct < 4; ++ct) {
        bf16x8 k0, k1;
        read_frag_pair(Ks, ct * 16 + l16, quad, k0, k1);
        f32x4 s = (f32x4){0.f, 0.f, 0.f, 0.f};
        s = __builtin_amdgcn_mfma_f32_16x16x32_bf16(qfrag[0], k0, s, 0, 0, 0);
        s = __builtin_amdgcn_mfma_f32_16x16x32_bf16(qfrag[1], k1, s, 0, 0, 0);
        sacc[ct] = s;
      }

      // ---- barrier-2 + next-tile stage (hides under softmax+PV) ----
      int padn[4];
      if (jt < it) {
        __syncthreads();   // all waves' K ds_reads complete -> Ks reusable
        stage_swz(Kb + base + (size_t)(jt + 1) * 4096, 64, Ks, tid);
        stage_swz(Vt + base + (jt + 1) * 64, 2048, Vs[cur ^ 1], tid);
#pragma unroll
        for (int ct = 0; ct < 4; ++ct)
          padn[ct] = pad[b * S_ + (jt + 1) * 64 + ct * 16 + l16];
      }

      // ---- masked online softmax (C-layout: row=quad*4+reg, col=ct*16+l16) ----
      const int grow0 = it * 64 + w * 16 + quad * 4;
      float alpha[4];
#pragma unroll
      for (int reg = 0; reg < 4; ++reg) {
        const int gi = grow0 + reg;
        float lg[4];
        float mx = -INFINITY;
#pragma unroll
        for (int ct = 0; ct < 4; ++ct) {
          int gj = jt * 64 + ct * 16 + l16;
          bool ok = (gj <= gi) && (padv[ct] != 0);
          lg[ct] = ok ? sacc[ct][reg] * 0.125f : -INFINITY;
          mx = fmaxf(mx, lg[ct]);
        }
#pragma unroll
        for (int off = 1; off < 16; off <<= 1) mx = fmaxf(mx, __shfl_xor(mx, off, 64));
        float mnew = fmaxf(mrow[reg], mx);
        float a    = __expf(mrow[reg] - mnew);
        float sm   = 0.f;
#pragma unroll
        for (int ct = 0; ct < 4; ++ct) {
          float pe = __expf(lg[ct] - mnew);
          sm += pe;
          Ps[w][quad * 4 + reg][ct * 16 + l16] = f2bf(pe);
        }
#pragma unroll
        for (int off = 1; off < 16; off <<= 1) sm += __shfl_xor(sm, off, 64);
        lrow[reg]  = lrow[reg] * a + sm;
        mrow[reg]  = mnew;
        alpha[reg] = a;
      }
#pragma unroll
      for (int dt = 0; dt < 4; ++dt)
#pragma unroll
        for (int reg = 0; reg < 4; ++reg) oacc[dt][reg] *= alpha[reg];

      // ---- P: C-layout -> A-layout via per-wave LDS strip (no barrier) ----
      bf16x8 pfrag0 = *(const bf16x8*)&Ps[w][l16][quad * 8];
      bf16x8 pfrag1 = *(const bf16x8*)&Ps[w][l16][32 + quad * 8];

      // ---- PV from LDS V tile (double-buffered; stage writes go to cur^1) ----
#pragma unroll
      for (int dt = 0; dt < 4; ++dt) {
        bf16x8 v0, v1;
        read_frag_pair(Vs[cur], dt * 16 + l16, quad, v0, v1);
        oacc[dt] = __builtin_amdgcn_mfma_f32_16x16x32_bf16(pfrag0, v0, oacc[dt], 0, 0, 0);
        oacc[dt] = __builtin_amdgcn_mfma_f32_16x16x32_bf16(pfrag1, v1, oacc[dt], 0, 0, 0);
      }

      if (jt < it) {
#pragma unroll
        for (int ct = 0; ct < 4; ++ct) padv[ct] = padn[ct];
        cur ^= 1;
      }
    }

    // epilogue: normalize, write bf16 in place over Qb (own rows only)
#pragma unroll
    for (int reg = 0; reg < 4; ++reg) {
      const float rl = 1.0f / lrow[reg];
      unsigned short* orow = Qb + base + (size_t)(it * 64 + w * 16 + quad * 4 + reg) * 64;
#pragma unroll
      for (int dt = 0; dt < 4; ++dt)
        orow[dt * 16 + l16] = f2bf(oacc[dt][reg] * rl);
    }
  }
}

// ---------------------------------------------------------------------------
// Residual + LayerNorm; O is bf16.
// ---------------------------------------------------------------------------
__global__ __launch_bounds__(256) void ln_kernel(
    const float* __restrict__ x, const unsigned short* __restrict__ O,
    const float* __restrict__ gamma, const float* __restrict__ beta,
    float* __restrict__ out)
{
  __shared__ float red[8];
  const int row = blockIdx.x;
  const int tid = threadIdx.x;
  float4 xv = ((const float4*)x)[(size_t)row * 256 + tid];
  us4 ov4 = *(const us4*)(O + (size_t)row * 1024 + tid * 4);
  float4 y = make_float4(xv.x + bf2f(ov4[0]), xv.y + bf2f(ov4[1]),
                         xv.z + bf2f(ov4[2]), xv.w + bf2f(ov4[3]));
  float s1 = y.x + y.y + y.z + y.w;
  float s2 = y.x*y.x + y.y*y.y + y.z*y.z + y.w*y.w;
#pragma unroll
  for (int off = 32; off >= 1; off >>= 1) {
    s1 += __shfl_xor(s1, off, 64);
    s2 += __shfl_xor(s2, off, 64);
  }
  if ((tid & 63) == 0) { red[tid >> 6] = s1; red[4 + (tid >> 6)] = s2; }
  __syncthreads();
  s1 = red[0] + red[1] + red[2] + red[3];
  s2 = red[4] + red[5] + red[6] + red[7];
  const float mean = s1 * (1.0f / 1024.0f);
  const float var  = fmaxf(s2 * (1.0f / 1024.0f) - mean * mean, 0.f);
  const float rstd = 1.0f / (sqrtf(var) + 1e-8f);
  float4 gv = ((const float4*)gamma)[tid];
  float4 bv = ((const float4*)beta)[tid];
  float4 r;
  r.x = gv.x * (y.x - mean) * rstd + bv.x;
  r.y = gv.y * (y.y - mean) * rstd + bv.y;
  r.z = gv.z * (y.z - mean) * rstd + bv.z;
  r.w = gv.w * (y.w - mean) * rstd + bv.w;
  ((float4*)out)[(size_t)row * 256 + tid] = r;
}

// ---------------------------------------------------------------------------
extern "C" void kernel_launch(void* const* d_in, const int* in_sizes, int n_in,
                              void* d_out, int out_size, void* d_ws, size_t ws_size,
                              hipStream_t stream)
{
  const float* q  = (const float*)d_in[0];
  const float* k  = (const float*)d_in[1];
  const float* v  = (const float*)d_in[2];
  // d_in[3] = causal tril mask — applied analytically (j<=i)
  const int*   pad = (const int*)d_in[4];
  const float* Wq = (const float*)d_in[5];
  const float* bq = (const float*)d_in[6];
  const float* Wk = (const float*)d_in[7];
  const float* bk = (const float*)d_in[8];
  const float* Wv = (const float*)d_in[9];
  const float* bv = (const float*)d_in[10];
  const float* Wo = (const float*)d_in[11];
  const float* bo = (const float*)d_in[12];
  const float* gamma = (const float*)d_in[13];
  const float* beta  = (const float*)d_in[14];
  float* out = (float*)d_out;

  char* ws = (char*)d_ws;
  const size_t MB = 1024 * 1024;
  unsigned short* Ac   = (unsigned short*)(ws);             // 16 MB bf16 staging
  unsigned short* Qb   = (unsigned short*)(ws + 16 * MB);   // 16 MB
  unsigned short* Kb   = (unsigned short*)(ws + 32 * MB);   // 16 MB
  unsigned short* Vb   = (unsigned short*)(ws + 48 * MB);   // 16 MB (flat V)
  unsigned short* Vtb  = (unsigned short*)(ws + 64 * MB);   // 16 MB (V^T per bh)
  unsigned short* Wall = (unsigned short*)(ws + 80 * MB);   // 8 MB (4 weights bf16)
  unsigned short* Obuf = Ac;                                // alias: Ac dead after V-GEMM

  dim3 gg(8, 64), bb(256);
  cvt_w<<<dim3(1024, 4), 256, 0, stream>>>(Wq, Wk, Wv, Wo, Wall);

  cvt_a<<<8192, 256, 0, stream>>>(q, Ac);
  gemm_mfma<<<gg, bb, 0, stream>>>(Ac, Wall + 0 * MB, bq, Qb);
  cvt_a<<<8192, 256, 0, stream>>>(k, Ac);
  gemm_mfma<<<gg, bb, 0, stream>>>(Ac, Wall + 1 * MB, bk, Kb);
  cvt_a<<<8192, 256, 0, stream>>>(v, Ac);
  gemm_mfma<<<gg, bb, 0, stream>>>(Ac, Wall + 2 * MB, bv, Vb);
  vtrans<<<dim3(32, 64), 256, 0, stream>>>(Vb, Vtb);

  attn_mfma<<<dim3(16, 64), 256, 0, stream>>>(Qb, Kb, Vtb, pad);  // Qb <- attn out

  gemm_mfma<<<gg, bb, 0, stream>>>(Qb, Wall + 3 * MB, bo, Obuf);
  ln_kernel<<<dim3(B_ * S_), 256, 0, stream>>>(q, Obuf, gamma, beta, out);
}

// Round 3
// 388.756 us; speedup vs baseline: 1.6652x; 1.1129x over previous
//
#include <hip/hip_runtime.h>
#include <hip/hip_bf16.h>
#include <math.h>

#define B_  4
#define S_  2048
#define D_  1024
#define H_  16
#define HD_ 64
#define SD_  (S_*D_)        // 2097152
#define SHD_ (S_*HD_)       // 131072

typedef __attribute__((ext_vector_type(8))) short          bf16x8;   // MFMA A/B frag (4 VGPRs)
typedef __attribute__((ext_vector_type(4))) float          f32x4;    // MFMA C/D frag
typedef __attribute__((ext_vector_type(8))) unsigned short us8;
typedef __attribute__((ext_vector_type(4))) unsigned short us4;

__device__ __forceinline__ unsigned short f2bf(float x) {  // RNE float->bf16
  unsigned int u = __float_as_uint(x);
  u += 0x7fffu + ((u >> 16) & 1u);
  return (unsigned short)(u >> 16);
}
__device__ __forceinline__ float bf2f(unsigned short u) {
  return __uint_as_float(((unsigned int)u) << 16);
}

// async global->LDS, 16B per lane: wave-uniform LDS base + lane*16 (m104).
__device__ __forceinline__ void gload16(const unsigned short* g, unsigned short* l) {
  __builtin_amdgcn_global_load_lds(
      (const __attribute__((address_space(1))) unsigned int*)g,
      (__attribute__((address_space(3))) unsigned int*)l,
      16, 0, 0);
}

// ---------------------------------------------------------------------------
// Stage a 64-row x 128-byte tile global->LDS with XOR-swizzled SOURCE, so
// that swizzled ds_reads (byte ^= (row&7)<<4) observe linear global data.
// ---------------------------------------------------------------------------
__device__ __forceinline__ void stage_swz(const unsigned short* __restrict__ g,
                                          int rstride /*elems*/,
                                          unsigned short* lds, int tid)
{
#pragma unroll
  for (int rr = 0; rr < 2; ++rr) {
    const int cidx = tid + rr * 256;               // 16B chunk index 0..511
    const int row  = cidx >> 3;                    // 0..63
    const int sb   = ((cidx & 7) * 16) ^ ((row & 7) << 4);  // swizzled src byte
    gload16(g + (size_t)row * rstride + (sb >> 1), lds + cidx * 8);
  }
}

// read one MFMA frag pair (cols [0,64) and [64,128) bytes of a tile row)
// from a swizzle-stored LDS tile.
__device__ __forceinline__ void read_frag_pair(const unsigned short* lds, int row,
                                               int quad, bf16x8& f0, bf16x8& f1)
{
  const int sw = (row & 7) << 4;
  const unsigned short* p = lds + row * 64;
  f0 = *(const bf16x8*)(p + (((quad * 16) ^ sw) >> 1));
  f1 = *(const bf16x8*)(p + (((64 + quad * 16) ^ sw) >> 1));
}

// ---------------------------------------------------------------------------
// fp32 -> bf16 converts
// ---------------------------------------------------------------------------
__global__ __launch_bounds__(256) void cvt_a(const float* __restrict__ s,
                                             unsigned short* __restrict__ d)
{
  int i = blockIdx.x * 256 + threadIdx.x;          // float4 index
  float4 v = ((const float4*)s)[i];
  us4 o = { f2bf(v.x), f2bf(v.y), f2bf(v.z), f2bf(v.w) };
  *(us4*)(d + (size_t)i * 4) = o;
}

// batched: q,k,v in one launch (blockIdx.y selects)
__global__ __launch_bounds__(256) void cvt3(const float* __restrict__ q,
                                            const float* __restrict__ k,
                                            const float* __restrict__ v,
                                            unsigned short* __restrict__ dst)
{
  const float* s = (blockIdx.y == 0) ? q : (blockIdx.y == 1) ? k : v;
  unsigned short* d = dst + (size_t)blockIdx.y * (B_ * (size_t)SD_);
  int i = blockIdx.x * 256 + threadIdx.x;
  float4 x = ((const float4*)s)[i];
  us4 o = { f2bf(x.x), f2bf(x.y), f2bf(x.z), f2bf(x.w) };
  *(us4*)(d + (size_t)i * 4) = o;
}

__global__ __launch_bounds__(256) void cvt_w(const float* __restrict__ w0,
                                             const float* __restrict__ w1,
                                             const float* __restrict__ w2,
                                             const float* __restrict__ w3,
                                             unsigned short* __restrict__ dst)
{
  const float* s = (blockIdx.y == 0) ? w0 : (blockIdx.y == 1) ? w1
                 : (blockIdx.y == 2) ? w2 : w3;
  unsigned short* d = dst + (size_t)blockIdx.y * 1024 * 1024;
  int i = blockIdx.x * 256 + threadIdx.x;
  float4 v = ((const float4*)s)[i];
  us4 o = { f2bf(v.x), f2bf(v.y), f2bf(v.z), f2bf(v.w) };
  *(us4*)(d + (size_t)i * 4) = o;
}

// pad int mask -> additive float mask (0 / -1e30); -1e30 not -inf (NaN safety)
__global__ __launch_bounds__(256) void pad_cvt(const int* __restrict__ pad,
                                               float* __restrict__ padf)
{
  int i = (blockIdx.x * 256 + threadIdx.x) * 4;
  int4 pv = *(const int4*)(pad + i);
  float4 o = { pv.x ? 0.f : -1e30f, pv.y ? 0.f : -1e30f,
               pv.z ? 0.f : -1e30f, pv.w ? 0.f : -1e30f };
  *(float4*)(padf + i) = o;
}

// ---------------------------------------------------------------------------
// bf16 MFMA GEMM body (m97 structure): C[8192,1024] = A @ W^T + bias, bf16 out
// 128x128 tile, BK=32, 256 thr = 4 waves (2x2), 4x4 16x16 tiles per wave.
// ---------------------------------------------------------------------------
__device__ __forceinline__ void gemm_body(
    const unsigned short* __restrict__ A,    // [8192,1024] bf16
    const unsigned short* __restrict__ Wb,   // [1024,1024] bf16, row n = out col
    const float* __restrict__ bias,
    unsigned short* __restrict__ Cb,
    int n0, int m0)
{
  __shared__ unsigned short As[128 * 32];   // [row][k] 8 KB
  __shared__ unsigned short Bs[128 * 32];   // [ncol][k] 8 KB

  const int tid  = threadIdx.x;
  const int lane = tid & 63;
  const int w    = tid >> 6;
  const int wm   = w >> 1, wn = w & 1;
  const int l16  = lane & 15, quad = lane >> 4;

  f32x4 acc[4][4];
#pragma unroll
  for (int mt = 0; mt < 4; ++mt)
#pragma unroll
    for (int nt = 0; nt < 4; ++nt) acc[mt][nt] = (f32x4){0.f, 0.f, 0.f, 0.f};

  const int srow = lane >> 2;          // 0..15 row within 16-row slab
  const int sseg = (lane & 3) * 8;     // ushort offset within 32-elem row

  for (int kt = 0; kt < 32; ++kt) {
    const int kofs = kt * 32;
#pragma unroll
    for (int t = 0; t < 2; ++t) {
      const int r = w * 32 + t * 16 + srow;          // 0..127
      gload16(A  + (size_t)(m0 + r) * 1024 + kofs + sseg, &As[r * 32 + sseg]);
      gload16(Wb + (size_t)(n0 + r) * 1024 + kofs + sseg, &Bs[r * 32 + sseg]);
    }
    __syncthreads();   // drains vmcnt (global_load_lds) + barrier

    bf16x8 af[4], bfr[4];
#pragma unroll
    for (int mt = 0; mt < 4; ++mt)
      af[mt] = *(const bf16x8*)&As[(wm * 64 + mt * 16 + l16) * 32 + quad * 8];
#pragma unroll
    for (int nt = 0; nt < 4; ++nt)
      bfr[nt] = *(const bf16x8*)&Bs[(wn * 64 + nt * 16 + l16) * 32 + quad * 8];
#pragma unroll
    for (int mt = 0; mt < 4; ++mt)
#pragma unroll
      for (int nt = 0; nt < 4; ++nt)
        acc[mt][nt] = __builtin_amdgcn_mfma_f32_16x16x32_bf16(
            af[mt], bfr[nt], acc[mt][nt], 0, 0, 0);
    __syncthreads();   // frag reads done before next stage overwrites
  }

  // C-layout: col=l16, row=quad*4+reg  (m89-verified)
#pragma unroll
  for (int nt = 0; nt < 4; ++nt) {
    const int ncol = n0 + wn * 64 + nt * 16 + l16;
    const float bv = bias[ncol];
#pragma unroll
    for (int mt = 0; mt < 4; ++mt) {
      const int row = m0 + wm * 64 + mt * 16 + quad * 4;
#pragma unroll
      for (int reg = 0; reg < 4; ++reg)
        Cb[(size_t)(row + reg) * 1024 + ncol] = f2bf(acc[mt][nt][reg] + bv);
    }
  }
}

__global__ __launch_bounds__(256) void gemm_mfma(
    const unsigned short* __restrict__ A, const unsigned short* __restrict__ Wb,
    const float* __restrict__ bias, unsigned short* __restrict__ Cb)
{
  gemm_body(A, Wb, bias, Cb, blockIdx.x * 128, blockIdx.y * 128);
}

// batched QKV projection: blockIdx.z selects {q,k,v}; 1536 WGs -> ~3 WG/CU
__global__ __launch_bounds__(256) void gemm_qkv(
    const unsigned short* __restrict__ A3,   // 3x [8192,1024] bf16
    const unsigned short* __restrict__ Wall, // 4x [1024,1024] bf16
    const float* __restrict__ bq, const float* __restrict__ bk,
    const float* __restrict__ bv,
    unsigned short* __restrict__ Qb, unsigned short* __restrict__ Kb,
    unsigned short* __restrict__ Vb)
{
  const int z = blockIdx.z;
  const unsigned short* A  = A3 + (size_t)z * (B_ * (size_t)SD_);
  const unsigned short* Wb = Wall + (size_t)z * 1024 * 1024;
  const float* bias = (z == 0) ? bq : (z == 1) ? bk : bv;
  unsigned short* Cb = (z == 0) ? Qb : (z == 1) ? Kb : Vb;
  gemm_body(A, Wb, bias, Cb, blockIdx.x * 128, blockIdx.y * 128);
}

// ---------------------------------------------------------------------------
// V transpose: Vt[bh][d][s] = Vflat[bh*131072 + s*64 + d]
// ---------------------------------------------------------------------------
__global__ __launch_bounds__(256) void vtrans(
    const unsigned short* __restrict__ V, unsigned short* __restrict__ Vt)
{
  __shared__ unsigned short t[64][72];   // t[s][d], padded rows
  const int tid = threadIdx.x;
  const int st  = blockIdx.x;            // s-tile 0..31
  const int bh  = blockIdx.y;            // 0..63
  const unsigned short* src = V + (size_t)bh * SHD_ + (size_t)st * 4096;

#pragma unroll
  for (int u = tid; u < 512; u += 256) {           // 512 us8 chunks = 8 KB
    us8 vv = ((const us8*)src)[u];
    int s  = u >> 3;
    int dg = (u & 7) * 8;
    *(us8*)&t[s][dg] = vv;
  }
  __syncthreads();

  unsigned short* dst = Vt + (size_t)bh * SHD_ + st * 64;
#pragma unroll
  for (int u = tid; u < 1024; u += 256) {          // 64 d-rows x 16 us4 chunks
    int d  = u >> 4;
    int s4 = (u & 15) * 4;
    us4 o = { t[s4][d], t[s4 + 1][d], t[s4 + 2][d], t[s4 + 3][d] };
    *(us4*)(dst + (size_t)d * 2048 + s4) = o;
  }
}

// ---------------------------------------------------------------------------
// MFMA flash attention: diagonal pairing + LDS-staged K/V + SWAPPED-QK SOFTMAX.
// QK^T computed as mfma(K, Q) -> score layout row=k(=quad*4+reg), col=q(=l16).
// The k-reduction is per-lane over 16 registers + 2 shfl_xor (16,32), replacing
// the old 32 ds_bpermute shuffle trees; softmax state (m,l) is ONE scalar/lane.
// Pad mask is additive (padf in {0,-1e30}); causal select only on the diagonal
// tile. Alpha crosses back to the O C-layout via 4 bpermutes/iter; P is stored
// to the per-wave LDS strip as us4 rows (q=l16, k contiguous) and re-read as
// the PV A-frag exactly as before.
// ---------------------------------------------------------------------------
__global__ __launch_bounds__(256, 4) void attn_mfma(
    unsigned short* __restrict__ Qb, const unsigned short* __restrict__ Kb,
    const unsigned short* __restrict__ Vt, const float* __restrict__ padf)
{
  __shared__ unsigned short Ks[64 * 64];        // 8 KB, single-buffered
  __shared__ unsigned short Vs[2][64 * 64];     // 16 KB, double-buffered
  __shared__ unsigned short Ps[4][16][72];      // per-wave P strip, 9 KB

  const int tid  = threadIdx.x;
  const int lane = tid & 63;
  const int w    = tid >> 6;
  const int p    = blockIdx.x;     // pair index 0..15
  const int bh   = blockIdx.y;     // 0..63
  const int b    = bh >> 4;
  const size_t base = (size_t)bh * SHD_;

  const int l16  = lane & 15;
  const int quad = lane >> 4;

  for (int half = 0; half < 2; ++half) {
    const int it = half ? (31 - p) : p;

    bf16x8 qfrag[2];   // Q rows w*16+l16 -> used as the B operand (columns q)
    {
      const unsigned short* qrow = Qb + base + (size_t)(it * 64 + w * 16 + l16) * 64;
      qfrag[0] = *(const bf16x8*)(qrow + quad * 8);
      qfrag[1] = *(const bf16x8*)(qrow + 32 + quad * 8);
    }

    f32x4 oacc[4];
#pragma unroll
    for (int dt = 0; dt < 4; ++dt) oacc[dt] = (f32x4){0.f, 0.f, 0.f, 0.f};
    float mS = -INFINITY, lS = 0.f;   // softmax state for q = it*64+w*16+l16

    // ---- half prologue: protect LDS from previous half, stage tile 0 ----
    __syncthreads();
    stage_swz(Kb + base, 64, Ks, tid);
    stage_swz(Vt + base, 2048, Vs[0], tid);
    float4 pf[4];
#pragma unroll
    for (int ct = 0; ct < 4; ++ct)
      pf[ct] = *(const float4*)(padf + b * S_ + ct * 16 + quad * 4);
    int cur = 0;

    for (int jt = 0; jt <= it; ++jt) {
      __syncthreads();   // barrier-1: staged K/V(jt) landed (vmcnt drain)

      // ---- QK^T swapped: A = K rows (ct tiles), B = Q ----
      f32x4 sacc[4];
#pragma unroll
      for (int ct = 0; ct < 4; ++ct) {
        bf16x8 k0, k1;
        read_frag_pair(Ks, ct * 16 + l16, quad, k0, k1);
        f32x4 s = (f32x4){0.f, 0.f, 0.f, 0.f};
        s = __builtin_amdgcn_mfma_f32_16x16x32_bf16(k0, qfrag[0], s, 0, 0, 0);
        s = __builtin_amdgcn_mfma_f32_16x16x32_bf16(k1, qfrag[1], s, 0, 0, 0);
        sacc[ct] = s;   // D[k=quad*4+reg (+ct*16)][q=l16]
      }

      // ---- barrier-2 + next-tile stage (hides under softmax+PV) ----
      float4 pfn[4];
      if (jt < it) {
        __syncthreads();   // all waves' K ds_reads complete -> Ks reusable
        stage_swz(Kb + base + (size_t)(jt + 1) * 4096, 64, Ks, tid);
        stage_swz(Vt + base + (jt + 1) * 64, 2048, Vs[cur ^ 1], tid);
#pragma unroll
        for (int ct = 0; ct < 4; ++ct)
          pfn[ct] = *(const float4*)(padf + b * S_ + (jt + 1) * 64 + ct * 16 + quad * 4);
      }

      // ---- swapped softmax: per-lane reduce over 16 regs + 2 shfl_xor ----
      float lg[4][4];
      float mx = -INFINITY;
#pragma unroll
      for (int ct = 0; ct < 4; ++ct)
#pragma unroll
        for (int reg = 0; reg < 4; ++reg) {
          float sc = fmaf(sacc[ct][reg], 0.125f, ((const float*)&pf[ct])[reg]);
          if (jt == it) {   // causal only needed on the diagonal tile
            bool ok = (ct * 16 + quad * 4 + reg) <= (w * 16 + l16);
            sc = ok ? sc : -1e30f;
          }
          lg[ct][reg] = sc;
          mx = fmaxf(mx, sc);
        }
      mx = fmaxf(mx, __shfl_xor(mx, 16, 64));
      mx = fmaxf(mx, __shfl_xor(mx, 32, 64));
      const float mnew = fmaxf(mS, mx);
      const float a    = __expf(mS - mnew);
      float sm = 0.f;
#pragma unroll
      for (int ct = 0; ct < 4; ++ct) {
        us4 pk;
#pragma unroll
        for (int reg = 0; reg < 4; ++reg) {
          float pe = __expf(lg[ct][reg] - mnew);
          sm += pe;
          pk[reg] = f2bf(pe);
        }
        *(us4*)&Ps[w][l16][ct * 16 + quad * 4] = pk;   // P[q=l16][k contig]
      }
      sm += __shfl_xor(sm, 16, 64);
      sm += __shfl_xor(sm, 32, 64);
      lS = lS * a + sm;
      mS = mnew;

      // ---- alpha to O C-layout (rows q = quad*4+reg) + rescale ----
      float aO[4];
#pragma unroll
      for (int reg = 0; reg < 4; ++reg) aO[reg] = __shfl(a, quad * 4 + reg, 64);
#pragma unroll
      for (int dt = 0; dt < 4; ++dt)
#pragma unroll
        for (int reg = 0; reg < 4; ++reg) oacc[dt][reg] *= aO[reg];

      // ---- PV: A-frag = P rows (LDS strip), B-frags = V^T rows from LDS ----
      bf16x8 pfrag0 = *(const bf16x8*)&Ps[w][l16][quad * 8];
      bf16x8 pfrag1 = *(const bf16x8*)&Ps[w][l16][32 + quad * 8];
#pragma unroll
      for (int dt = 0; dt < 4; ++dt) {
        bf16x8 v0, v1;
        read_frag_pair(Vs[cur], dt * 16 + l16, quad, v0, v1);
        oacc[dt] = __builtin_amdgcn_mfma_f32_16x16x32_bf16(pfrag0, v0, oacc[dt], 0, 0, 0);
        oacc[dt] = __builtin_amdgcn_mfma_f32_16x16x32_bf16(pfrag1, v1, oacc[dt], 0, 0, 0);
      }

      if (jt < it) {
#pragma unroll
        for (int ct = 0; ct < 4; ++ct) pf[ct] = pfn[ct];
        cur ^= 1;
      }
    }

    // epilogue: l back to O layout, normalize, write bf16 in place over Qb
    float lO[4];
#pragma unroll
    for (int reg = 0; reg < 4; ++reg) lO[reg] = __shfl(lS, quad * 4 + reg, 64);
#pragma unroll
    for (int reg = 0; reg < 4; ++reg) {
      const float rl = 1.0f / lO[reg];
      unsigned short* orow = Qb + base + (size_t)(it * 64 + w * 16 + quad * 4 + reg) * 64;
#pragma unroll
      for (int dt = 0; dt < 4; ++dt)
        orow[dt * 16 + l16] = f2bf(oacc[dt][reg] * rl);
    }
  }
}

// ---------------------------------------------------------------------------
// Residual + LayerNorm; O is bf16.
// ---------------------------------------------------------------------------
__global__ __launch_bounds__(256) void ln_kernel(
    const float* __restrict__ x, const unsigned short* __restrict__ O,
    const float* __restrict__ gamma, const float* __restrict__ beta,
    float* __restrict__ out)
{
  __shared__ float red[8];
  const int row = blockIdx.x;
  const int tid = threadIdx.x;
  float4 xv = ((const float4*)x)[(size_t)row * 256 + tid];
  us4 ov4 = *(const us4*)(O + (size_t)row * 1024 + tid * 4);
  float4 y = make_float4(xv.x + bf2f(ov4[0]), xv.y + bf2f(ov4[1]),
                         xv.z + bf2f(ov4[2]), xv.w + bf2f(ov4[3]));
  float s1 = y.x + y.y + y.z + y.w;
  float s2 = y.x*y.x + y.y*y.y + y.z*y.z + y.w*y.w;
#pragma unroll
  for (int off = 32; off >= 1; off >>= 1) {
    s1 += __shfl_xor(s1, off, 64);
    s2 += __shfl_xor(s2, off, 64);
  }
  if ((tid & 63) == 0) { red[tid >> 6] = s1; red[4 + (tid >> 6)] = s2; }
  __syncthreads();
  s1 = red[0] + red[1] + red[2] + red[3];
  s2 = red[4] + red[5] + red[6] + red[7];
  const float mean = s1 * (1.0f / 1024.0f);
  const float var  = fmaxf(s2 * (1.0f / 1024.0f) - mean * mean, 0.f);
  const float rstd = 1.0f / (sqrtf(var) + 1e-8f);
  float4 gv = ((const float4*)gamma)[tid];
  float4 bv = ((const float4*)beta)[tid];
  float4 r;
  r.x = gv.x * (y.x - mean) * rstd + bv.x;
  r.y = gv.y * (y.y - mean) * rstd + bv.y;
  r.z = gv.z * (y.z - mean) * rstd + bv.z;
  r.w = gv.w * (y.w - mean) * rstd + bv.w;
  ((float4*)out)[(size_t)row * 256 + tid] = r;
}

// ---------------------------------------------------------------------------
extern "C" void kernel_launch(void* const* d_in, const int* in_sizes, int n_in,
                              void* d_out, int out_size, void* d_ws, size_t ws_size,
                              hipStream_t stream)
{
  const float* q  = (const float*)d_in[0];
  const float* k  = (const float*)d_in[1];
  const float* v  = (const float*)d_in[2];
  // d_in[3] = causal tril mask — applied analytically (j<=i)
  const int*   pad = (const int*)d_in[4];
  const float* Wq = (const float*)d_in[5];
  const float* bq = (const float*)d_in[6];
  const float* Wk = (const float*)d_in[7];
  const float* bk = (const float*)d_in[8];
  const float* Wv = (const float*)d_in[9];
  const float* bv = (const float*)d_in[10];
  const float* Wo = (const float*)d_in[11];
  const float* bo = (const float*)d_in[12];
  const float* gamma = (const float*)d_in[13];
  const float* beta  = (const float*)d_in[14];
  float* out = (float*)d_out;

  char* ws = (char*)d_ws;
  const size_t MB = 1024 * 1024;
  dim3 gg(8, 64), bb(256);

  if (ws_size >= 121 * MB) {
    // ---- batched layout: 120 MB + padf ----
    unsigned short* Ac3  = (unsigned short*)(ws);             // 48 MB (q,k,v bf16)
    unsigned short* Qb   = (unsigned short*)(ws + 48 * MB);
    unsigned short* Kb   = (unsigned short*)(ws + 64 * MB);
    unsigned short* Vb   = (unsigned short*)(ws + 80 * MB);
    unsigned short* Vtb  = (unsigned short*)(ws + 96 * MB);
    unsigned short* Wall = (unsigned short*)(ws + 112 * MB);  // 8 MB
    float*          padf = (float*)(ws + 120 * MB);           // 32 KB
    unsigned short* Obuf = Ac3;                               // alias: dead after V-GEMM

    cvt_w<<<dim3(1024, 4), 256, 0, stream>>>(Wq, Wk, Wv, Wo, Wall);
    pad_cvt<<<8, 256, 0, stream>>>(pad, padf);
    cvt3<<<dim3(8192, 3), 256, 0, stream>>>(q, k, v, Ac3);
    gemm_qkv<<<dim3(8, 64, 3), bb, 0, stream>>>(Ac3, Wall, bq, bk, bv, Qb, Kb, Vb);
    vtrans<<<dim3(32, 64), 256, 0, stream>>>(Vb, Vtb);
    attn_mfma<<<dim3(16, 64), 256, 0, stream>>>(Qb, Kb, Vtb, padf);
    gemm_mfma<<<gg, bb, 0, stream>>>(Qb, Wall + 3 * MB, bo, Obuf);
    ln_kernel<<<dim3(B_ * S_), 256, 0, stream>>>(q, Obuf, gamma, beta, out);
  } else {
    // ---- sequential fallback (88 MB + padf) ----
    unsigned short* Ac   = (unsigned short*)(ws);
    unsigned short* Qb   = (unsigned short*)(ws + 16 * MB);
    unsigned short* Kb   = (unsigned short*)(ws + 32 * MB);
    unsigned short* Vb   = (unsigned short*)(ws + 48 * MB);
    unsigned short* Vtb  = (unsigned short*)(ws + 64 * MB);
    unsigned short* Wall = (unsigned short*)(ws + 80 * MB);
    float*          padf = (float*)(ws + 88 * MB);
    unsigned short* Obuf = Ac;

    cvt_w<<<dim3(1024, 4), 256, 0, stream>>>(Wq, Wk, Wv, Wo, Wall);
    pad_cvt<<<8, 256, 0, stream>>>(pad, padf);
    cvt_a<<<8192, 256, 0, stream>>>(q, Ac);
    gemm_mfma<<<gg, bb, 0, stream>>>(Ac, Wall + 0 * MB, bq, Qb);
    cvt_a<<<8192, 256, 0, stream>>>(k, Ac);
    gemm_mfma<<<gg, bb, 0, stream>>>(Ac, Wall + 1 * MB, bk, Kb);
    cvt_a<<<8192, 256, 0, stream>>>(v, Ac);
    gemm_mfma<<<gg, bb, 0, stream>>>(Ac, Wall + 2 * MB, bv, Vb);
    vtrans<<<dim3(32, 64), 256, 0, stream>>>(Vb, Vtb);
    attn_mfma<<<dim3(16, 64), 256, 0, stream>>>(Qb, Kb, Vtb, padf);
    gemm_mfma<<<gg, bb, 0, stream>>>(Qb, Wall + 3 * MB, bo, Obuf);
    ln_kernel<<<dim3(B_ * S_), 256, 0, stream>>>(q, Obuf, gamma, beta, out);
  }
}

// Round 4
// 381.412 us; speedup vs baseline: 1.6973x; 1.0193x over previous
//
#include <hip/hip_runtime.h>
#include <hip/hip_bf16.h>
#include <math.h>

#define B_  4
#define S_  2048
#define D_  1024
#define H_  16
#define HD_ 64
#define SD_  (S_*D_)        // 2097152
#define SHD_ (S_*HD_)       // 131072

typedef __attribute__((ext_vector_type(8))) short          bf16x8;   // MFMA A/B frag (4 VGPRs)
typedef __attribute__((ext_vector_type(4))) float          f32x4;    // MFMA C/D frag
typedef __attribute__((ext_vector_type(8))) unsigned short us8;
typedef __attribute__((ext_vector_type(4))) unsigned short us4;

__device__ __forceinline__ unsigned short f2bf(float x) {  // RNE float->bf16
  unsigned int u = __float_as_uint(x);
  u += 0x7fffu + ((u >> 16) & 1u);
  return (unsigned short)(u >> 16);
}
__device__ __forceinline__ float bf2f(unsigned short u) {
  return __uint_as_float(((unsigned int)u) << 16);
}

// async global->LDS, 16B per lane: wave-uniform LDS base + lane*16 (m104).
__device__ __forceinline__ void gload16(const unsigned short* g, unsigned short* l) {
  __builtin_amdgcn_global_load_lds(
      (const __attribute__((address_space(1))) unsigned int*)g,
      (__attribute__((address_space(3))) unsigned int*)l,
      16, 0, 0);
}

// ---------------------------------------------------------------------------
// Stage a 64-row x 128-byte tile global->LDS with XOR-swizzled SOURCE, so
// that swizzled ds_reads (byte ^= (row&7)<<4) observe linear global data.
// ---------------------------------------------------------------------------
__device__ __forceinline__ void stage_swz(const unsigned short* __restrict__ g,
                                          int rstride /*elems*/,
                                          unsigned short* lds, int tid)
{
#pragma unroll
  for (int rr = 0; rr < 2; ++rr) {
    const int cidx = tid + rr * 256;               // 16B chunk index 0..511
    const int row  = cidx >> 3;                    // 0..63
    const int sb   = ((cidx & 7) * 16) ^ ((row & 7) << 4);  // swizzled src byte
    gload16(g + (size_t)row * rstride + (sb >> 1), lds + cidx * 8);
  }
}

// read one MFMA frag pair (cols [0,64) and [64,128) bytes of a tile row)
// from a swizzle-stored LDS tile.
__device__ __forceinline__ void read_frag_pair(const unsigned short* lds, int row,
                                               int quad, bf16x8& f0, bf16x8& f1)
{
  const int sw = (row & 7) << 4;
  const unsigned short* p = lds + row * 64;
  f0 = *(const bf16x8*)(p + (((quad * 16) ^ sw) >> 1));
  f1 = *(const bf16x8*)(p + (((64 + quad * 16) ^ sw) >> 1));
}

// ---------------------------------------------------------------------------
// fp32 -> bf16 converts (fallback path kernels kept)
// ---------------------------------------------------------------------------
__global__ __launch_bounds__(256) void cvt_a(const float* __restrict__ s,
                                             unsigned short* __restrict__ d)
{
  int i = blockIdx.x * 256 + threadIdx.x;          // float4 index
  float4 v = ((const float4*)s)[i];
  us4 o = { f2bf(v.x), f2bf(v.y), f2bf(v.z), f2bf(v.w) };
  *(us4*)(d + (size_t)i * 4) = o;
}

__global__ __launch_bounds__(256) void cvt_w(const float* __restrict__ w0,
                                             const float* __restrict__ w1,
                                             const float* __restrict__ w2,
                                             const float* __restrict__ w3,
                                             unsigned short* __restrict__ dst)
{
  const float* s = (blockIdx.y == 0) ? w0 : (blockIdx.y == 1) ? w1
                 : (blockIdx.y == 2) ? w2 : w3;
  unsigned short* d = dst + (size_t)blockIdx.y * 1024 * 1024;
  int i = blockIdx.x * 256 + threadIdx.x;
  float4 v = ((const float4*)s)[i];
  us4 o = { f2bf(v.x), f2bf(v.y), f2bf(v.z), f2bf(v.w) };
  *(us4*)(d + (size_t)i * 4) = o;
}

// pad int mask -> additive float mask (0 / -1e30); -1e30 not -inf (NaN safety)
__global__ __launch_bounds__(256) void pad_cvt(const int* __restrict__ pad,
                                               float* __restrict__ padf)
{
  int i = (blockIdx.x * 256 + threadIdx.x) * 4;
  int4 pv = *(const int4*)(pad + i);
  float4 o = { pv.x ? 0.f : -1e30f, pv.y ? 0.f : -1e30f,
               pv.z ? 0.f : -1e30f, pv.w ? 0.f : -1e30f };
  *(float4*)(padf + i) = o;
}

// ---------------------------------------------------------------------------
// merged converts: qkv (24576 WGs) + weights (4096 WGs) + pad (8 WGs)
// ---------------------------------------------------------------------------
__global__ __launch_bounds__(256) void cvt_all(
    const float* __restrict__ q, const float* __restrict__ k,
    const float* __restrict__ v,
    const float* __restrict__ w0, const float* __restrict__ w1,
    const float* __restrict__ w2, const float* __restrict__ w3,
    const int* __restrict__ pad,
    unsigned short* __restrict__ Ac3, unsigned short* __restrict__ Wall,
    float* __restrict__ padf)
{
  const int bx = blockIdx.x;
  if (bx < 24576) {
    const int y = bx >> 13;                       // 0..2
    const int i = (bx & 8191) * 256 + threadIdx.x;
    const float* s = (y == 0) ? q : (y == 1) ? k : v;
    unsigned short* d = Ac3 + (size_t)y * (B_ * (size_t)SD_);
    float4 x = ((const float4*)s)[i];
    us4 o = { f2bf(x.x), f2bf(x.y), f2bf(x.z), f2bf(x.w) };
    *(us4*)(d + (size_t)i * 4) = o;
  } else if (bx < 24576 + 4096) {
    const int bw = bx - 24576;
    const int y = bw >> 10;                       // 0..3
    const int i = (bw & 1023) * 256 + threadIdx.x;
    const float* s = (y == 0) ? w0 : (y == 1) ? w1 : (y == 2) ? w2 : w3;
    unsigned short* d = Wall + (size_t)y * 1024 * 1024;
    float4 x = ((const float4*)s)[i];
    us4 o = { f2bf(x.x), f2bf(x.y), f2bf(x.z), f2bf(x.w) };
    *(us4*)(d + (size_t)i * 4) = o;
  } else {
    const int i = ((bx - 28672) * 256 + threadIdx.x) * 4;   // 8192 ints total
    int4 pv = *(const int4*)(pad + i);
    float4 o = { pv.x ? 0.f : -1e30f, pv.y ? 0.f : -1e30f,
                 pv.z ? 0.f : -1e30f, pv.w ? 0.f : -1e30f };
    *(float4*)(padf + i) = o;
  }
}

// ---------------------------------------------------------------------------
// bf16 MFMA GEMM body: C[8192,1024] = A @ W^T + bias, bf16 out.
// 128x128 tile, BK=32, 4 waves (2x2), 4x4 16x16 tiles per wave.
// ROUND-4: double-buffered LDS + counted s_waitcnt vmcnt(4): next tile's
// global_load_lds flies under current tile's ds_read+MFMA. At 2 WG/CU the
// old stage->vmcnt(0)-drain->compute loop exposed the full tile latency.
// ---------------------------------------------------------------------------
__device__ __forceinline__ void gemm_body(
    const unsigned short* __restrict__ A,    // [8192,1024] bf16
    const unsigned short* __restrict__ Wb,   // [1024,1024] bf16, row n = out col
    const float* __restrict__ bias,
    unsigned short* __restrict__ Cb,
    int n0, int m0)
{
  __shared__ unsigned short As[2][128 * 32];   // 2 x 8 KB
  __shared__ unsigned short Bs[2][128 * 32];   // 2 x 8 KB

  const int tid  = threadIdx.x;
  const int lane = tid & 63;
  const int w    = tid >> 6;
  const int wm   = w >> 1, wn = w & 1;
  const int l16  = lane & 15, quad = lane >> 4;

  f32x4 acc[4][4];
#pragma unroll
  for (int mt = 0; mt < 4; ++mt)
#pragma unroll
    for (int nt = 0; nt < 4; ++nt) acc[mt][nt] = (f32x4){0.f, 0.f, 0.f, 0.f};

  const int srow = lane >> 2;          // 0..15 row within 16-row slab
  const int sseg = (lane & 3) * 8;     // ushort offset within 32-elem row
  const int r0   = w * 32 + srow;      // this thread's two rows: r0, r0+16

  const unsigned short* Ar0 = A  + (size_t)(m0 + r0) * 1024 + sseg;
  const unsigned short* Ar1 = A  + (size_t)(m0 + r0 + 16) * 1024 + sseg;
  const unsigned short* Br0 = Wb + (size_t)(n0 + r0) * 1024 + sseg;
  const unsigned short* Br1 = Wb + (size_t)(n0 + r0 + 16) * 1024 + sseg;

  auto STAGE = [&](int buf, int kt) {
    const int ko = kt * 32;
    gload16(Ar0 + ko, &As[buf][r0 * 32 + sseg]);
    gload16(Ar1 + ko, &As[buf][(r0 + 16) * 32 + sseg]);
    gload16(Br0 + ko, &Bs[buf][r0 * 32 + sseg]);
    gload16(Br1 + ko, &Bs[buf][(r0 + 16) * 32 + sseg]);
  };

  STAGE(0, 0);
  int cur = 0;
  for (int kt = 0; kt < 32; ++kt) {
    if (kt < 31) {
      STAGE(cur ^ 1, kt + 1);                       // prefetch next tile
      asm volatile("s_waitcnt vmcnt(4)" ::: "memory");   // wait CURRENT tile only
    } else {
      asm volatile("s_waitcnt vmcnt(0)" ::: "memory");
    }
    __builtin_amdgcn_sched_barrier(0);   // rule #18: pin the wait
    __builtin_amdgcn_s_barrier();        // all waves' current tile landed

    bf16x8 af[4], bfr[4];
#pragma unroll
    for (int mt = 0; mt < 4; ++mt)
      af[mt] = *(const bf16x8*)&As[cur][(wm * 64 + mt * 16 + l16) * 32 + quad * 8];
#pragma unroll
    for (int nt = 0; nt < 4; ++nt)
      bfr[nt] = *(const bf16x8*)&Bs[cur][(wn * 64 + nt * 16 + l16) * 32 + quad * 8];
#pragma unroll
    for (int mt = 0; mt < 4; ++mt)
#pragma unroll
      for (int nt = 0; nt < 4; ++nt)
        acc[mt][nt] = __builtin_amdgcn_mfma_f32_16x16x32_bf16(
            af[mt], bfr[nt], acc[mt][nt], 0, 0, 0);

    __builtin_amdgcn_sched_barrier(0);   // keep ds_read+MFMA before barrier-2
    __builtin_amdgcn_s_barrier();        // reads done before buf overwritten
    cur ^= 1;
  }

  // C-layout: col=l16, row=quad*4+reg  (m89-verified)
#pragma unroll
  for (int nt = 0; nt < 4; ++nt) {
    const int ncol = n0 + wn * 64 + nt * 16 + l16;
    const float bv = bias[ncol];
#pragma unroll
    for (int mt = 0; mt < 4; ++mt) {
      const int row = m0 + wm * 64 + mt * 16 + quad * 4;
#pragma unroll
      for (int reg = 0; reg < 4; ++reg)
        Cb[(size_t)(row + reg) * 1024 + ncol] = f2bf(acc[mt][nt][reg] + bv);
    }
  }
}

// bijective XCD swizzle over the (x,y) grid plane: nwg = 512 (%8==0)
__device__ __forceinline__ void xcd_coords(int& n0, int& m0)
{
  const int nwgx = gridDim.x;
  const int nwg  = nwgx * gridDim.y;
  const int bid  = blockIdx.y * nwgx + blockIdx.x;
  const int sw   = (bid & 7) * (nwg >> 3) + (bid >> 3);
  n0 = (sw % nwgx) * 128;
  m0 = (sw / nwgx) * 128;
}

__global__ __launch_bounds__(256) void gemm_mfma(
    const unsigned short* __restrict__ A, const unsigned short* __restrict__ Wb,
    const float* __restrict__ bias, unsigned short* __restrict__ Cb)
{
  int n0, m0;
  xcd_coords(n0, m0);
  gemm_body(A, Wb, bias, Cb, n0, m0);
}

// batched QKV projection: blockIdx.z selects {q,k,v}
__global__ __launch_bounds__(256) void gemm_qkv(
    const unsigned short* __restrict__ A3,   // 3x [8192,1024] bf16
    const unsigned short* __restrict__ Wall, // 4x [1024,1024] bf16
    const float* __restrict__ bq, const float* __restrict__ bk,
    const float* __restrict__ bv,
    unsigned short* __restrict__ Qb, unsigned short* __restrict__ Kb,
    unsigned short* __restrict__ Vb)
{
  const int z = blockIdx.z;
  const unsigned short* A  = A3 + (size_t)z * (B_ * (size_t)SD_);
  const unsigned short* Wb = Wall + (size_t)z * 1024 * 1024;
  const float* bias = (z == 0) ? bq : (z == 1) ? bk : bv;
  unsigned short* Cb = (z == 0) ? Qb : (z == 1) ? Kb : Vb;
  int n0, m0;
  xcd_coords(n0, m0);
  gemm_body(A, Wb, bias, Cb, n0, m0);
}

// ---------------------------------------------------------------------------
// V transpose: Vt[bh][d][s] = Vflat[bh*131072 + s*64 + d]
// ---------------------------------------------------------------------------
__global__ __launch_bounds__(256) void vtrans(
    const unsigned short* __restrict__ V, unsigned short* __restrict__ Vt)
{
  __shared__ unsigned short t[64][72];   // t[s][d], padded rows
  const int tid = threadIdx.x;
  const int st  = blockIdx.x;            // s-tile 0..31
  const int bh  = blockIdx.y;            // 0..63
  const unsigned short* src = V + (size_t)bh * SHD_ + (size_t)st * 4096;

#pragma unroll
  for (int u = tid; u < 512; u += 256) {           // 512 us8 chunks = 8 KB
    us8 vv = ((const us8*)src)[u];
    int s  = u >> 3;
    int dg = (u & 7) * 8;
    *(us8*)&t[s][dg] = vv;
  }
  __syncthreads();

  unsigned short* dst = Vt + (size_t)bh * SHD_ + st * 64;
#pragma unroll
  for (int u = tid; u < 1024; u += 256) {          // 64 d-rows x 16 us4 chunks
    int d  = u >> 4;
    int s4 = (u & 15) * 4;
    us4 o = { t[s4][d], t[s4 + 1][d], t[s4 + 2][d], t[s4 + 3][d] };
    *(us4*)(dst + (size_t)d * 2048 + s4) = o;
  }
}

// ---------------------------------------------------------------------------
// MFMA flash attention: diagonal pairing + LDS-staged K/V + SWAPPED-QK SOFTMAX.
// (unchanged from round 3 — 91 µs, verified)
// ---------------------------------------------------------------------------
__global__ __launch_bounds__(256, 4) void attn_mfma(
    unsigned short* __restrict__ Qb, const unsigned short* __restrict__ Kb,
    const unsigned short* __restrict__ Vt, const float* __restrict__ padf)
{
  __shared__ unsigned short Ks[64 * 64];        // 8 KB, single-buffered
  __shared__ unsigned short Vs[2][64 * 64];     // 16 KB, double-buffered
  __shared__ unsigned short Ps[4][16][72];      // per-wave P strip, 9 KB

  const int tid  = threadIdx.x;
  const int lane = tid & 63;
  const int w    = tid >> 6;
  const int p    = blockIdx.x;     // pair index 0..15
  const int bh   = blockIdx.y;     // 0..63
  const int b    = bh >> 4;
  const size_t base = (size_t)bh * SHD_;

  const int l16  = lane & 15;
  const int quad = lane >> 4;

  for (int half = 0; half < 2; ++half) {
    const int it = half ? (31 - p) : p;

    bf16x8 qfrag[2];   // Q rows w*16+l16 -> used as the B operand (columns q)
    {
      const unsigned short* qrow = Qb + base + (size_t)(it * 64 + w * 16 + l16) * 64;
      qfrag[0] = *(const bf16x8*)(qrow + quad * 8);
      qfrag[1] = *(const bf16x8*)(qrow + 32 + quad * 8);
    }

    f32x4 oacc[4];
#pragma unroll
    for (int dt = 0; dt < 4; ++dt) oacc[dt] = (f32x4){0.f, 0.f, 0.f, 0.f};
    float mS = -INFINITY, lS = 0.f;   // softmax state for q = it*64+w*16+l16

    // ---- half prologue: protect LDS from previous half, stage tile 0 ----
    __syncthreads();
    stage_swz(Kb + base, 64, Ks, tid);
    stage_swz(Vt + base, 2048, Vs[0], tid);
    float4 pf[4];
#pragma unroll
    for (int ct = 0; ct < 4; ++ct)
      pf[ct] = *(const float4*)(padf + b * S_ + ct * 16 + quad * 4);
    int cur = 0;

    for (int jt = 0; jt <= it; ++jt) {
      __syncthreads();   // barrier-1: staged K/V(jt) landed (vmcnt drain)

      // ---- QK^T swapped: A = K rows (ct tiles), B = Q ----
      f32x4 sacc[4];
#pragma unroll
      for (int ct = 0; ct < 4; ++ct) {
        bf16x8 k0, k1;
        read_frag_pair(Ks, ct * 16 + l16, quad, k0, k1);
        f32x4 s = (f32x4){0.f, 0.f, 0.f, 0.f};
        s = __builtin_amdgcn_mfma_f32_16x16x32_bf16(k0, qfrag[0], s, 0, 0, 0);
        s = __builtin_amdgcn_mfma_f32_16x16x32_bf16(k1, qfrag[1], s, 0, 0, 0);
        sacc[ct] = s;   // D[k=quad*4+reg (+ct*16)][q=l16]
      }

      // ---- barrier-2 + next-tile stage (hides under softmax+PV) ----
      float4 pfn[4];
      if (jt < it) {
        __syncthreads();   // all waves' K ds_reads complete -> Ks reusable
        stage_swz(Kb + base + (size_t)(jt + 1) * 4096, 64, Ks, tid);
        stage_swz(Vt + base + (jt + 1) * 64, 2048, Vs[cur ^ 1], tid);
#pragma unroll
        for (int ct = 0; ct < 4; ++ct)
          pfn[ct] = *(const float4*)(padf + b * S_ + (jt + 1) * 64 + ct * 16 + quad * 4);
      }

      // ---- swapped softmax: per-lane reduce over 16 regs + 2 shfl_xor ----
      float lg[4][4];
      float mx = -INFINITY;
#pragma unroll
      for (int ct = 0; ct < 4; ++ct)
#pragma unroll
        for (int reg = 0; reg < 4; ++reg) {
          float sc = fmaf(sacc[ct][reg], 0.125f, ((const float*)&pf[ct])[reg]);
          if (jt == it) {   // causal only needed on the diagonal tile
            bool ok = (ct * 16 + quad * 4 + reg) <= (w * 16 + l16);
            sc = ok ? sc : -1e30f;
          }
          lg[ct][reg] = sc;
          mx = fmaxf(mx, sc);
        }
      mx = fmaxf(mx, __shfl_xor(mx, 16, 64));
      mx = fmaxf(mx, __shfl_xor(mx, 32, 64));
      const float mnew = fmaxf(mS, mx);
      const float a    = __expf(mS - mnew);
      float sm = 0.f;
#pragma unroll
      for (int ct = 0; ct < 4; ++ct) {
        us4 pk;
#pragma unroll
        for (int reg = 0; reg < 4; ++reg) {
          float pe = __expf(lg[ct][reg] - mnew);
          sm += pe;
          pk[reg] = f2bf(pe);
        }
        *(us4*)&Ps[w][l16][ct * 16 + quad * 4] = pk;   // P[q=l16][k contig]
      }
      sm += __shfl_xor(sm, 16, 64);
      sm += __shfl_xor(sm, 32, 64);
      lS = lS * a + sm;
      mS = mnew;

      // ---- alpha to O C-layout (rows q = quad*4+reg) + rescale ----
      float aO[4];
#pragma unroll
      for (int reg = 0; reg < 4; ++reg) aO[reg] = __shfl(a, quad * 4 + reg, 64);
#pragma unroll
      for (int dt = 0; dt < 4; ++dt)
#pragma unroll
        for (int reg = 0; reg < 4; ++reg) oacc[dt][reg] *= aO[reg];

      // ---- PV: A-frag = P rows (LDS strip), B-frags = V^T rows from LDS ----
      bf16x8 pfrag0 = *(const bf16x8*)&Ps[w][l16][quad * 8];
      bf16x8 pfrag1 = *(const bf16x8*)&Ps[w][l16][32 + quad * 8];
#pragma unroll
      for (int dt = 0; dt < 4; ++dt) {
        bf16x8 v0, v1;
        read_frag_pair(Vs[cur], dt * 16 + l16, quad, v0, v1);
        oacc[dt] = __builtin_amdgcn_mfma_f32_16x16x32_bf16(pfrag0, v0, oacc[dt], 0, 0, 0);
        oacc[dt] = __builtin_amdgcn_mfma_f32_16x16x32_bf16(pfrag1, v1, oacc[dt], 0, 0, 0);
      }

      if (jt < it) {
#pragma unroll
        for (int ct = 0; ct < 4; ++ct) pf[ct] = pfn[ct];
        cur ^= 1;
      }
    }

    // epilogue: l back to O layout, normalize, write bf16 in place over Qb
    float lO[4];
#pragma unroll
    for (int reg = 0; reg < 4; ++reg) lO[reg] = __shfl(lS, quad * 4 + reg, 64);
#pragma unroll
    for (int reg = 0; reg < 4; ++reg) {
      const float rl = 1.0f / lO[reg];
      unsigned short* orow = Qb + base + (size_t)(it * 64 + w * 16 + quad * 4 + reg) * 64;
#pragma unroll
      for (int dt = 0; dt < 4; ++dt)
        orow[dt * 16 + l16] = f2bf(oacc[dt][reg] * rl);
    }
  }
}

// ---------------------------------------------------------------------------
// Residual + LayerNorm; O is bf16.
// ---------------------------------------------------------------------------
__global__ __launch_bounds__(256) void ln_kernel(
    const float* __restrict__ x, const unsigned short* __restrict__ O,
    const float* __restrict__ gamma, const float* __restrict__ beta,
    float* __restrict__ out)
{
  __shared__ float red[8];
  const int row = blockIdx.x;
  const int tid = threadIdx.x;
  float4 xv = ((const float4*)x)[(size_t)row * 256 + tid];
  us4 ov4 = *(const us4*)(O + (size_t)row * 1024 + tid * 4);
  float4 y = make_float4(xv.x + bf2f(ov4[0]), xv.y + bf2f(ov4[1]),
                         xv.z + bf2f(ov4[2]), xv.w + bf2f(ov4[3]));
  float s1 = y.x + y.y + y.z + y.w;
  float s2 = y.x*y.x + y.y*y.y + y.z*y.z + y.w*y.w;
#pragma unroll
  for (int off = 32; off >= 1; off >>= 1) {
    s1 += __shfl_xor(s1, off, 64);
    s2 += __shfl_xor(s2, off, 64);
  }
  if ((tid & 63) == 0) { red[tid >> 6] = s1; red[4 + (tid >> 6)] = s2; }
  __syncthreads();
  s1 = red[0] + red[1] + red[2] + red[3];
  s2 = red[4] + red[5] + red[6] + red[7];
  const float mean = s1 * (1.0f / 1024.0f);
  const float var  = fmaxf(s2 * (1.0f / 1024.0f) - mean * mean, 0.f);
  const float rstd = 1.0f / (sqrtf(var) + 1e-8f);
  float4 gv = ((const float4*)gamma)[tid];
  float4 bv = ((const float4*)beta)[tid];
  float4 r;
  r.x = gv.x * (y.x - mean) * rstd + bv.x;
  r.y = gv.y * (y.y - mean) * rstd + bv.y;
  r.z = gv.z * (y.z - mean) * rstd + bv.z;
  r.w = gv.w * (y.w - mean) * rstd + bv.w;
  ((float4*)out)[(size_t)row * 256 + tid] = r;
}

// ---------------------------------------------------------------------------
extern "C" void kernel_launch(void* const* d_in, const int* in_sizes, int n_in,
                              void* d_out, int out_size, void* d_ws, size_t ws_size,
                              hipStream_t stream)
{
  const float* q  = (const float*)d_in[0];
  const float* k  = (const float*)d_in[1];
  const float* v  = (const float*)d_in[2];
  // d_in[3] = causal tril mask — applied analytically (j<=i)
  const int*   pad = (const int*)d_in[4];
  const float* Wq = (const float*)d_in[5];
  const float* bq = (const float*)d_in[6];
  const float* Wk = (const float*)d_in[7];
  const float* bk = (const float*)d_in[8];
  const float* Wv = (const float*)d_in[9];
  const float* bv = (const float*)d_in[10];
  const float* Wo = (const float*)d_in[11];
  const float* bo = (const float*)d_in[12];
  const float* gamma = (const float*)d_in[13];
  const float* beta  = (const float*)d_in[14];
  float* out = (float*)d_out;

  char* ws = (char*)d_ws;
  const size_t MB = 1024 * 1024;
  dim3 gg(8, 64), bb(256);

  if (ws_size >= 121 * MB) {
    // ---- batched layout: 120 MB + padf ----
    unsigned short* Ac3  = (unsigned short*)(ws);             // 48 MB (q,k,v bf16)
    unsigned short* Qb   = (unsigned short*)(ws + 48 * MB);
    unsigned short* Kb   = (unsigned short*)(ws + 64 * MB);
    unsigned short* Vb   = (unsigned short*)(ws + 80 * MB);
    unsigned short* Vtb  = (unsigned short*)(ws + 96 * MB);
    unsigned short* Wall = (unsigned short*)(ws + 112 * MB);  // 8 MB
    float*          padf = (float*)(ws + 120 * MB);           // 32 KB
    unsigned short* Obuf = Ac3;                               // alias: dead after V-GEMM

    cvt_all<<<dim3(28680), 256, 0, stream>>>(q, k, v, Wq, Wk, Wv, Wo, pad,
                                             Ac3, Wall, padf);
    gemm_qkv<<<dim3(8, 64, 3), bb, 0, stream>>>(Ac3, Wall, bq, bk, bv, Qb, Kb, Vb);
    vtrans<<<dim3(32, 64), 256, 0, stream>>>(Vb, Vtb);
    attn_mfma<<<dim3(16, 64), 256, 0, stream>>>(Qb, Kb, Vtb, padf);
    gemm_mfma<<<gg, bb, 0, stream>>>(Qb, Wall + 3 * MB, bo, Obuf);
    ln_kernel<<<dim3(B_ * S_), 256, 0, stream>>>(q, Obuf, gamma, beta, out);
  } else {
    // ---- sequential fallback (88 MB + padf) ----
    unsigned short* Ac   = (unsigned short*)(ws);
    unsigned short* Qb   = (unsigned short*)(ws + 16 * MB);
    unsigned short* Kb   = (unsigned short*)(ws + 32 * MB);
    unsigned short* Vb   = (unsigned short*)(ws + 48 * MB);
    unsigned short* Vtb  = (unsigned short*)(ws + 64 * MB);
    unsigned short* Wall = (unsigned short*)(ws + 80 * MB);
    float*          padf = (float*)(ws + 88 * MB);
    unsigned short* Obuf = Ac;

    cvt_w<<<dim3(1024, 4), 256, 0, stream>>>(Wq, Wk, Wv, Wo, Wall);
    pad_cvt<<<8, 256, 0, stream>>>(pad, padf);
    cvt_a<<<8192, 256, 0, stream>>>(q, Ac);
    gemm_mfma<<<gg, bb, 0, stream>>>(Ac, Wall + 0 * MB, bq, Qb);
    cvt_a<<<8192, 256, 0, stream>>>(k, Ac);
    gemm_mfma<<<gg, bb, 0, stream>>>(Ac, Wall + 1 * MB, bk, Kb);
    cvt_a<<<8192, 256, 0, stream>>>(v, Ac);
    gemm_mfma<<<gg, bb, 0, stream>>>(Ac, Wall + 2 * MB, bv, Vb);
    vtrans<<<dim3(32, 64), 256, 0, stream>>>(Vb, Vtb);
    attn_mfma<<<dim3(16, 64), 256, 0, stream>>>(Qb, Kb, Vtb, padf);
    gemm_mfma<<<gg, bb, 0, stream>>>(Qb, Wall + 3 * MB, bo, Obuf);
    ln_kernel<<<dim3(B_ * S_), 256, 0, stream>>>(q, Obuf, gamma, beta, out);
  }
}